// Round 3
// baseline (712.749 us; speedup 1.0000x reference)
//
#include <hip/hip_runtime.h>
#include <hip/hip_cooperative_groups.h>

namespace cg = cooperative_groups;

#define T_STEPS 2000
#define NN 39
#define K1 2496          // 39*64, original K
#define K2 4992          // hi/lo duplicated K
#define KS 6             // K-splits in gemm1 (partial buffers, no atomics)
#define KSP 832          // K2 per split = 13 chunks of 64
#define KCHUNKS 13
#define CH_L 50
#define CH_W 50
#define NCH 40           // 40*50 = 2000
#define GRID 256

using short8 = __attribute__((ext_vector_type(8))) short;
using floatx4 = __attribute__((ext_vector_type(4))) float;

struct Params {
    const float* x; const int* ei; const float* Wc; const float* bc;
    const float* W1; const float* b1; const float* W2; const float* b2;
    const float* W3; const float* b3; float* out;
    float* AH; float* H1; float* H2; float* H3;
    float* F1p; float* G2; float* G3; float* PART;
    unsigned int* W1t; unsigned char* FS; unsigned char* S1; unsigned char* S2;
};

__device__ __forceinline__ unsigned int bf16_rne(float v) {
    unsigned int u = __float_as_uint(v);
    return (u + 0x7FFFu + ((u >> 16) & 1u)) >> 16;
}

__global__ __launch_bounds__(256) void fused(Params p) {
    cg::grid_group grid = cg::this_grid();
    __shared__ __align__(16) float smemf[6144];   // 24.5 KB, reused per phase
    const int bid = blockIdx.x, tid = threadIdx.x;

    // ================= P0: A_hat (block 0) || W1 -> bf16 hi/lo (blocks 1..255) ===========
    if (bid == 0) {
        float* A = smemf;            // 1521
        float* dinv = smemf + 1536;  // 39
        for (int u = tid; u < NN * NN; u += 256) A[u] = 0.0f;
        __syncthreads();
        if (tid < 156) {
            int r = p.ei[tid], c = p.ei[156 + tid];
            atomicAdd(&A[c * NN + r], 1.0f);
        }
        __syncthreads();
        if (tid < NN) {
            float d = 0.0f;
            for (int u = 0; u < NN; ++u) d += A[tid * NN + u];
            dinv[tid] = (d > 0.0f) ? (1.0f / sqrtf(d)) : 0.0f;
        }
        __syncthreads();
        for (int u = tid; u < NN * NN; u += 256) {
            int i = u / NN, j = u % NN;
            p.AH[u] = (dinv[i] * A[u]) * dinv[j];
        }
    } else {
        const int total = 128 * K1;
        for (int f = (bid - 1) * 256 + tid; f < total; f += 255 * 256) {
            int j = f / K1, k = f - j * K1;
            float w = p.W1[k * 128 + j];
            unsigned int hi = bf16_rne(w);
            float r = w - __uint_as_float(hi << 16);     // exact
            unsigned int lo = bf16_rne(r);
            p.W1t[j * K1 + k] = (hi & 0xFFFFu) | (lo << 16);
        }
    }
    __threadfence();
    grid.sync();

    // ================= P1: fused 3-hop TAGConv propagation, 125 t-tiles of 16 ============
    {
        float* ah = smemf;          // 1521 (pad to 1536)
        float* xs = smemf + 1536;   // 1248 (pad to 1280)
        float* hb = smemf + 2816;   // 1248
        for (int tile = bid; tile < 125; tile += GRID) {
            int t0 = tile * 16;
            for (int u = tid; u < NN * NN; u += 256) ah[u] = p.AH[u];
            for (int e = tid; e < 78 * 16; e += 256) {
                int r = e >> 4, tt = e & 15;
                xs[e] = p.x[r * T_STEPS + t0 + tt];
            }
            __syncthreads();
            // stage 1: xs -> hb
            for (int e = tid; e < 1248; e += 256) {
                int r = e >> 4, tt = e & 15;
                int i = r >> 1, c = r & 1;
                float acc = 0.0f;
                #pragma unroll
                for (int m = 0; m < NN; ++m)
                    acc += ah[i * NN + m] * xs[(2 * m + c) * 16 + tt];
                hb[e] = acc;
            }
            __syncthreads();
            for (int e = tid; e < 1248; e += 256) {
                int r = e >> 4, tt = e & 15;
                p.H1[r * T_STEPS + t0 + tt] = hb[e];
            }
            // stage 2: hb -> xs
            for (int e = tid; e < 1248; e += 256) {
                int r = e >> 4, tt = e & 15;
                int i = r >> 1, c = r & 1;
                float acc = 0.0f;
                #pragma unroll
                for (int m = 0; m < NN; ++m)
                    acc += ah[i * NN + m] * hb[(2 * m + c) * 16 + tt];
                xs[e] = acc;
            }
            __syncthreads();
            for (int e = tid; e < 1248; e += 256) {
                int r = e >> 4, tt = e & 15;
                p.H2[r * T_STEPS + t0 + tt] = xs[e];
            }
            // stage 3: xs -> hb
            for (int e = tid; e < 1248; e += 256) {
                int r = e >> 4, tt = e & 15;
                int i = r >> 1, c = r & 1;
                float acc = 0.0f;
                #pragma unroll
                for (int m = 0; m < NN; ++m)
                    acc += ah[i * NN + m] * xs[(2 * m + c) * 16 + tt];
                hb[e] = acc;
            }
            __syncthreads();
            for (int e = tid; e < 1248; e += 256) {
                int r = e >> 4, tt = e & 15;
                p.H3[r * T_STEPS + t0 + tt] = hb[e];
            }
            __syncthreads();   // hb/xs/ah reused next tile
        }
    }
    __threadfence();
    grid.sync();

    // ================= P2: layer-1 scan (conv fused), 400 logical blocks ================
    for (int lb = bid; lb < 10 * NCH; lb += GRID) {
        int nb = lb % 10, chunk = lb / 10;
        int n = nb * 256 + tid;
        if (n < K1) {
            int i = n >> 6, j = n & 63;
            const float* bases[4] = {p.x, p.H1, p.H2, p.H3};
            const float* hp[8];
            float wv[8];
            #pragma unroll
            for (int k = 0; k < 4; ++k)
                #pragma unroll
                for (int c = 0; c < 2; ++c) {
                    hp[k * 2 + c] = bases[k] + (i * 2 + c) * T_STEPS;
                    wv[k * 2 + c] = p.Wc[(k * 2 + c) * 64 + j];
                }
            float bias = p.bc[j];
            int t0 = chunk * CH_L;
            int tw = t0 - CH_W; if (tw < 0) tw = 0;
            float m = 0.0f, s = 0.0f;
            for (int t = tw; t < t0; ++t) {
                float acc = 0.0f;
                #pragma unroll
                for (int q = 0; q < 8; ++q) acc += wv[q] * hp[q][t];
                float v = acc + bias;
                m = m * 0.2f * (1.0f - s) + v;
                s = (m > 0.5f) ? 1.0f : 0.0f;
            }
            for (int t = t0; t < t0 + CH_L; ++t) {
                float acc = 0.0f;
                #pragma unroll
                for (int q = 0; q < 8; ++q) acc += wv[q] * hp[q][t];
                float v = acc + bias;
                m = m * 0.2f * (1.0f - s) + v;
                s = (m > 0.5f) ? 1.0f : 0.0f;
                p.FS[t * K1 + n] = (unsigned char)(s != 0.0f);
            }
        }
    }
    __threadfence();
    grid.sync();

    // ================= P3: gemm1 MFMA bf16 hi/lo, 63 t-tiles x 6 K-splits ===============
    {
        short* As = (short*)smemf;           // 32*72
        short* Ws = (short*)smemf + 2304;    // 128*72
        const short* W1s = (const short*)p.W1t;
        int lane = tid & 63;
        int wv = tid >> 6;
        int j0 = wv * 32;
        int row = lane & 15;
        int quad = lane >> 4;
        int sm = tid >> 3;
        int sb4 = (tid & 7) * 4;
        for (int lb = bid; lb < 63 * KS; lb += GRID) {
            int tb = lb % 63, ks = lb / 63;
            int t0 = tb * 32;
            int kb_orig = ks * 416;
            int kb2 = ks * KSP;
            floatx4 acc00 = {0.f, 0.f, 0.f, 0.f};
            floatx4 acc01 = acc00, acc10 = acc00, acc11 = acc00;
            for (int c = 0; c < KCHUNKS; ++c) {
                unsigned int u4 = 0;
                int gt = t0 + sm;
                if (gt < T_STEPS)
                    u4 = *(const unsigned int*)&p.FS[gt * K1 + kb_orig + c * 32 + sb4];
                uint4 dd;
                dd.x = (u4 & 0x000000FFu) ? 0x3F803F80u : 0u;
                dd.y = (u4 & 0x0000FF00u) ? 0x3F803F80u : 0u;
                dd.z = (u4 & 0x00FF0000u) ? 0x3F803F80u : 0u;
                dd.w = (u4 & 0xFF000000u) ? 0x3F803F80u : 0u;
                *(uint4*)&As[sm * 72 + sb4 * 2] = dd;
                #pragma unroll
                for (int u = 0; u < 4; ++u) {
                    int aid = u * 256 + tid;
                    int jj = aid >> 3;
                    int ko = (aid & 7) * 8;
                    short8 w = *(const short8*)&W1s[jj * K2 + kb2 + c * 64 + ko];
                    *(short8*)&Ws[jj * 72 + ko] = w;
                }
                __syncthreads();
                #pragma unroll
                for (int s = 0; s < 2; ++s) {
                    int k0 = s * 32 + quad * 8;
                    short8 a0 = *(const short8*)&As[row * 72 + k0];
                    short8 a1 = *(const short8*)&As[(row + 16) * 72 + k0];
                    short8 b0 = *(const short8*)&Ws[(j0 + row) * 72 + k0];
                    short8 b1 = *(const short8*)&Ws[(j0 + 16 + row) * 72 + k0];
                    acc00 = __builtin_amdgcn_mfma_f32_16x16x32_bf16(a0, b0, acc00, 0, 0, 0);
                    acc01 = __builtin_amdgcn_mfma_f32_16x16x32_bf16(a0, b1, acc01, 0, 0, 0);
                    acc10 = __builtin_amdgcn_mfma_f32_16x16x32_bf16(a1, b0, acc10, 0, 0, 0);
                    acc11 = __builtin_amdgcn_mfma_f32_16x16x32_bf16(a1, b1, acc11, 0, 0, 0);
                }
                __syncthreads();
            }
            float* outp = p.F1p + (size_t)ks * T_STEPS * 128;
            #pragma unroll
            for (int r = 0; r < 4; ++r) {
                int m0 = quad * 4 + r;
                int t = t0 + m0;
                if (t < T_STEPS) {
                    outp[t * 128 + j0 + row]      = acc00[r];
                    outp[t * 128 + j0 + 16 + row] = acc01[r];
                }
                int t2 = t0 + 16 + m0;
                if (t2 < T_STEPS) {
                    outp[t2 * 128 + j0 + row]      = acc10[r];
                    outp[t2 * 128 + j0 + 16 + row] = acc11[r];
                }
            }
        }
    }
    __threadfence();
    grid.sync();

    // ================= P4: h1 scan (sums 6 partials), 40 chunks =========================
    for (int lb = bid; lb < NCH; lb += GRID) {
        if (tid < 128) {
            int n = tid;
            int t0 = lb * CH_L;
            int tw = t0 - CH_W; if (tw < 0) tw = 0;
            float b = p.b1[n];
            float m = 0.0f, s = 0.0f;
            const float* p0 = p.F1p + n;
            for (int t = tw; t < t0; ++t) {
                float v = 0.0f;
                #pragma unroll
                for (int q = 0; q < KS; ++q) v += p0[(size_t)q * T_STEPS * 128 + t * 128];
                v += b;
                m = m * 0.2f * (1.0f - s) + v;
                s = (m > 0.5f) ? 1.0f : 0.0f;
            }
            for (int t = t0; t < t0 + CH_L; ++t) {
                float v = 0.0f;
                #pragma unroll
                for (int q = 0; q < KS; ++q) v += p0[(size_t)q * T_STEPS * 128 + t * 128];
                v += b;
                m = m * 0.2f * (1.0f - s) + v;
                s = (m > 0.5f) ? 1.0f : 0.0f;
                p.S1[t * 128 + n] = (unsigned char)(s != 0.0f);
            }
        }
    }
    __threadfence();
    grid.sync();

    // ================= P5: gemm2  G2[t][j] = S1[t][:] @ W2, 125 t-tiles of 16 ===========
    {
        float* AT = smemf;   // [k][t] 128*16
        for (int lb = bid; lb < 125; lb += GRID) {
            int t0 = lb * 16;
            {
                int t = tid >> 4, k0 = (tid & 15) * 8;
                const uchar4* q = (const uchar4*)&p.S1[(t0 + t) * 128 + k0];
                uchar4 b0 = q[0], b1v = q[1];
                AT[(k0 + 0) * 16 + t] = (float)b0.x;
                AT[(k0 + 1) * 16 + t] = (float)b0.y;
                AT[(k0 + 2) * 16 + t] = (float)b0.z;
                AT[(k0 + 3) * 16 + t] = (float)b0.w;
                AT[(k0 + 4) * 16 + t] = (float)b1v.x;
                AT[(k0 + 5) * 16 + t] = (float)b1v.y;
                AT[(k0 + 6) * 16 + t] = (float)b1v.z;
                AT[(k0 + 7) * 16 + t] = (float)b1v.w;
            }
            __syncthreads();
            int j = tid;
            float acc[16] = {0.0f};
            for (int k = 0; k < 128; ++k) {
                float w = p.W2[k * 256 + j];
                float4 a0 = *(const float4*)&AT[k * 16 + 0];
                float4 a1 = *(const float4*)&AT[k * 16 + 4];
                float4 a2 = *(const float4*)&AT[k * 16 + 8];
                float4 a3 = *(const float4*)&AT[k * 16 + 12];
                acc[0]  += a0.x * w; acc[1]  += a0.y * w; acc[2]  += a0.z * w; acc[3]  += a0.w * w;
                acc[4]  += a1.x * w; acc[5]  += a1.y * w; acc[6]  += a1.z * w; acc[7]  += a1.w * w;
                acc[8]  += a2.x * w; acc[9]  += a2.y * w; acc[10] += a2.z * w; acc[11] += a2.w * w;
                acc[12] += a3.x * w; acc[13] += a3.y * w; acc[14] += a3.z * w; acc[15] += a3.w * w;
            }
            #pragma unroll
            for (int tt = 0; tt < 16; ++tt) p.G2[(t0 + tt) * 256 + j] = acc[tt];
            __syncthreads();
        }
    }
    __threadfence();
    grid.sync();

    // ================= P6: h2 scan, 40 chunks ===========================================
    for (int lb = bid; lb < NCH; lb += GRID) {
        int n = tid;
        int t0 = lb * CH_L;
        int tw = t0 - CH_W; if (tw < 0) tw = 0;
        float b = p.b2[n];
        float m = 0.0f, s = 0.0f;
        for (int t = tw; t < t0; ++t) {
            float v = p.G2[t * 256 + n] + b;
            m = m * 0.2f * (1.0f - s) + v;
            s = (m > 0.5f) ? 1.0f : 0.0f;
        }
        for (int t = t0; t < t0 + CH_L; ++t) {
            float v = p.G2[t * 256 + n] + b;
            m = m * 0.2f * (1.0f - s) + v;
            s = (m > 0.5f) ? 1.0f : 0.0f;
            p.S2[t * 256 + n] = (unsigned char)(s != 0.0f);
        }
    }
    __threadfence();
    grid.sync();

    // ================= P7: gemm3  G3[t][j] = S2[t][:] @ W3 (72000 outputs) ==============
    for (int e = bid * 256 + tid; e < T_STEPS * 36; e += GRID * 256) {
        int t = e / 36, j = e - t * 36;
        float acc = 0.0f;
        for (int k = 0; k < 256; ++k) {
            float a = (float)p.S2[t * 256 + k];
            acc += a * p.W3[k * 36 + j];
        }
        p.G3[e] = acc;
    }
    __threadfence();
    grid.sync();

    // ================= P8: h3 scan + spike counts, 40 chunks ============================
    for (int lb = bid; lb < NCH; lb += GRID) {
        if (tid < 36) {
            int n = tid;
            int t0 = lb * CH_L;
            int tw = t0 - CH_W; if (tw < 0) tw = 0;
            float b = p.b3[n];
            float m = 0.0f, s = 0.0f;
            int cnt = 0;
            for (int t = tw; t < t0; ++t) {
                float v = p.G3[t * 36 + n] + b;
                m = m * 0.2f * (1.0f - s) + v;
                s = (m > 0.5f) ? 1.0f : 0.0f;
            }
            for (int t = t0; t < t0 + CH_L; ++t) {
                float v = p.G3[t * 36 + n] + b;
                m = m * 0.2f * (1.0f - s) + v;
                s = (m > 0.5f) ? 1.0f : 0.0f;
                cnt += (s != 0.0f) ? 1 : 0;
            }
            p.PART[lb * 36 + n] = (float)cnt;
        }
    }
    __threadfence();
    grid.sync();

    // ================= P9: finalize =====================================================
    if (bid == 0 && tid < 36) {
        float sum = 0.0f;
        for (int c = 0; c < NCH; ++c) sum += p.PART[c * 36 + tid];
        p.out[tid] = sum / 2000.0f;
    }
}

extern "C" void kernel_launch(void* const* d_in, const int* in_sizes, int n_in,
                              void* d_out, int out_size, void* d_ws, size_t ws_size,
                              hipStream_t stream) {
    Params p;
    p.x  = (const float*)d_in[0];
    p.ei = (const int*)d_in[1];
    p.Wc = (const float*)d_in[2];
    p.bc = (const float*)d_in[3];
    p.W1 = (const float*)d_in[4];
    p.b1 = (const float*)d_in[5];
    p.W2 = (const float*)d_in[6];
    p.b2 = (const float*)d_in[7];
    p.W3 = (const float*)d_in[8];
    p.b3 = (const float*)d_in[9];
    p.out = (float*)d_out;

    float* w = (float*)d_ws;
    p.AH  = w;                    w += 1536;
    p.H1  = w;                    w += 156000;
    p.H2  = w;                    w += 156000;
    p.H3  = w;                    w += 156000;
    p.F1p = w;                    w += (size_t)KS * T_STEPS * 128;
    p.G2  = w;                    w += (size_t)T_STEPS * 256;
    p.G3  = w;                    w += (size_t)T_STEPS * 36;
    p.PART = w;                   w += NCH * 36 + 60;
    p.W1t = (unsigned int*)w;     w += 128 * K1;
    unsigned char* cb = (unsigned char*)w;
    p.FS = cb;                    cb += (size_t)T_STEPS * K1;
    p.S1 = cb;                    cb += (size_t)T_STEPS * 128;
    p.S2 = cb;

    void* args[] = {(void*)&p};
    hipLaunchCooperativeKernel((const void*)fused, dim3(GRID), dim3(256), args, 0, stream);
}